// Round 5
// baseline (320.532 us; speedup 1.0000x reference)
//
#include <hip/hip_runtime.h>

// GCN 2-layer + pool + head, R20: block-major partition (private L2-resident regions).
// R19's k_part (84us) was still serialization-bound (VALU 3.4%, occ 15%) with 5.7x write
// amplification (92MB/16MB): bucket-major layout interleaves ~32B chunks from 256 blocks
// in every line -> cross-XCD partial-line thrash, plus LDS counting-sort barriers.
// Fix: block-major intermediate. Each block scatters its tile into its PRIVATE contiguous
// region [b*tile, b*tile+tile) grouped by bucket via LDS cursors only. Region ~62KB ->
// 2MB/XCD, L2-resident, lines fully written once. k_part = bh-row scan + streaming
// scatter; no staging, no sub-tiles, ~3 barriers. Run boundaries go to bof[b][k]
// (streaming write). k_grp gathers its bucket's 256 runs via a 256-entry LDS run-prefix
// + 8-step binary search; XCD-bijective swizzle makes consecutive buckets share L2.
// Downstream (k_csr/k_mid/k_pool/k_final) unchanged.
//   h[c] = b + dinv[c]*( g[c] + sum_e w_e * g[row_e] ),  g = dinv * (prev @ W)

#define SH 6
#define RB 64
#define KMAX 2048           // N <= 131072 (row packs in 17 bits)
#define TPB 256
#define BCAP 8192           // per-bucket LDS capacity in k_grp
#define PT 256              // k_part threads
#define PB 256              // partition grid (= k_cnt grid)
#define KST (KMAX + 1)      // bof row stride

typedef unsigned short ushort_t;
typedef unsigned char u8;

__device__ __forceinline__ ushort_t f2bf(float v) {
    unsigned u = __float_as_uint(v);
    u += 0x7FFFu + ((u >> 16) & 1u);   // RNE
    return (ushort_t)(u >> 16);
}

__device__ __forceinline__ unsigned quantw(float w) {
    unsigned wq = (unsigned)__float2int_rn(w * 32768.0f);
    return wq > 32767u ? 32767u : wq;
}

// ---------- bucket counts, tile-aligned; stores per-block hist for k_part ----------
__global__ __launch_bounds__(TPB)
void k_cnt(const int* __restrict__ col, unsigned* __restrict__ bcnt,
           unsigned* __restrict__ bh, int E, int K, int tile) {
    __shared__ unsigned lh[KMAX];
    int e0 = blockIdx.x * tile, e1 = min(e0 + tile, E);
    for (int i = threadIdx.x; i < K; i += TPB) lh[i] = 0u;
    __syncthreads();
    for (int e = e0 + threadIdx.x; e < e1; e += TPB)
        atomicAdd(&lh[col[e] >> SH], 1u);
    __syncthreads();
    for (int i = threadIdx.x; i < K; i += TPB) {
        unsigned c = lh[i];
        bh[(size_t)blockIdx.x * KMAX + i] = c;
        if (c) atomicAdd(&bcnt[i], c);
    }
}

// ---------- exclusive scan over bucket counts -> bst (srt layout) ----------
__global__ void k_scan(const unsigned* __restrict__ cnt, unsigned* __restrict__ start,
                       int K) {
    __shared__ unsigned a[KMAX], b[KMAX];
    int t = threadIdx.x;  // 1024
    for (int i = t; i < KMAX; i += 1024) a[i] = (i < K) ? cnt[i] : 0u;
    __syncthreads();
    unsigned *src = a, *dst = b;
    for (int off = 1; off < KMAX; off <<= 1) {
        for (int i = t; i < KMAX; i += 1024)
            dst[i] = (i >= off) ? src[i] + src[i - off] : src[i];
        __syncthreads();
        unsigned* tmp = src; src = dst; dst = tmp;
    }
    for (int i = t; i < K; i += 1024) start[i] = (i == 0) ? 0u : src[i - 1];
}

// ---------- block-major partition: private region, bucket-grouped, L2-resident ----------
__global__ __launch_bounds__(PT)
void k_part(const int* __restrict__ row, const int* __restrict__ col,
            const float* __restrict__ ew, const unsigned* __restrict__ bh,
            unsigned* __restrict__ bof, unsigned* __restrict__ brp,
            u8* __restrict__ bcl, int E, int K, int tile) {
    __shared__ unsigned lcur[KMAX];              // 8KB scatter cursors
    __shared__ unsigned wt[PT / 64];
    int tid = threadIdx.x, b = blockIdx.x;
    int e0 = b * tile; if (e0 > E) e0 = E;
    int e1 = min(b * tile + tile, E);
    unsigned base = (unsigned)e0;

    // exclusive scan of this block's bh row (KMAX entries, 8 serial per thread)
    const int per = KMAX / PT;                   // 8
    unsigned a[per];
    unsigned ts = 0;
    int i0 = tid * per;
#pragma unroll
    for (int q = 0; q < per; q++) {
        a[q] = (i0 + q < K) ? bh[(size_t)b * KMAX + i0 + q] : 0u;
        ts += a[q];
    }
    unsigned v = ts;
#pragma unroll
    for (int o = 1; o < 64; o <<= 1) {
        unsigned u = __shfl_up(v, o, 64);
        if ((tid & 63) >= o) v += u;
    }
    if ((tid & 63) == 63) wt[tid >> 6] = v;
    __syncthreads();
    if (tid == 0) {
        unsigned acc = 0;
#pragma unroll
        for (int w = 0; w < PT / 64; w++) { unsigned t = wt[w]; wt[w] = acc; acc += t; }
    }
    __syncthreads();
    unsigned run = wt[tid >> 6] + (v - ts);      // exclusive prefix at i0
    unsigned* bo = bof + (size_t)b * KST;        // streaming row write
#pragma unroll
    for (int q = 0; q < per; q++) {
        unsigned val = base + run;
        lcur[i0 + q] = val;
        bo[i0 + q] = val;
        run += a[q];
    }
    if (tid == PT - 1) bo[KMAX] = base + run;    // covers K == KMAX edge case
    __syncthreads();

    // streaming scatter into private region (random within ~62KB -> L2 absorbs)
    for (int e = e0 + tid; e < e1; e += PT) {
        int c = col[e];
        unsigned pos = atomicAdd(&lcur[c >> SH], 1u);
        brp[pos] = (unsigned)row[e] | (quantw(ew[e]) << 17);
        bcl[pos] = (u8)(c & 63);
    }
}

// ---------- per-bucket: gather 256 runs -> group-by-col -> srt + cptr + dinv + g1/acc1 ----
__global__ __launch_bounds__(TPB)
void k_grp(const unsigned* __restrict__ brp, const u8* __restrict__ bcl,
           const unsigned* __restrict__ bof, const unsigned* __restrict__ bst,
           const float* __restrict__ x, const float* __restrict__ W1,
           unsigned* __restrict__ srt, unsigned* __restrict__ cptr,
           float* __restrict__ dinv, unsigned* __restrict__ g1b,
           float* __restrict__ acc1, int N, int E, int K) {
    // bijective XCD-contiguous swizzle (m204): consecutive buckets share an XCD's L2
    int orig = blockIdx.x;
    int q8 = K >> 3, r8 = K & 7;
    int xcd = orig & 7, idx = orig >> 3;
    int k = (xcd < r8 ? xcd * (q8 + 1) : r8 * (q8 + 1) + (xcd - r8) * q8) + idx;
    int node0 = k << SH;

    __shared__ unsigned ebuf[BCAP];          // 32KB (reused as gtmp after scatter)
    __shared__ u8 cbuf[BCAP];                // 8KB
    __shared__ unsigned rsrc[PB];            // run source starts
    __shared__ unsigned roff[PB + 1];        // exclusive prefix of run lengths
    __shared__ unsigned wt4[TPB / 64];
    __shared__ unsigned cnt64[RB], st64[RB], dq[RB];
    __shared__ float dl[RB], lx[RB * 3], lw[48];
    int tid = threadIdx.x;
    unsigned s = bst[k];
    if (tid < RB) { cnt64[tid] = 0u; dq[tid] = 0u; }
    if (tid < 48) lw[tid] = W1[tid];
    int nn = min(RB, N - node0);
    for (int i = tid; i < nn * 3; i += TPB) lx[i] = x[(size_t)node0 * 3 + i];

    // run table: rsrc/len from bof columns k, k+1; 256-entry exclusive scan
    unsigned rl = 0;
    {
        unsigned s0 = bof[(size_t)tid * KST + k];
        unsigned s1 = bof[(size_t)tid * KST + k + 1];
        rsrc[tid] = s0;
        rl = s1 - s0;
    }
    unsigned v = rl;
#pragma unroll
    for (int o = 1; o < 64; o <<= 1) {
        unsigned u = __shfl_up(v, o, 64);
        if ((tid & 63) >= o) v += u;
    }
    if ((tid & 63) == 63) wt4[tid >> 6] = v;
    __syncthreads();
    if (tid == 0) {
        unsigned acc = 0;
#pragma unroll
        for (int w = 0; w < TPB / 64; w++) { unsigned t = wt4[w]; wt4[w] = acc; acc += t; }
    }
    __syncthreads();
    unsigned ex = wt4[tid >> 6] + (v - rl);
    roff[tid] = ex;
    if (tid == PB - 1) roff[PB] = ex + rl;
    __syncthreads();
    unsigned c = roff[PB];

    // j -> source index in brp/bcl: binary search run, then offset
#define MAP_SRC(j, srcv)                                                       \
    {                                                                          \
        int lo = 0, hi = PB - 1;                                               \
        _Pragma("unroll")                                                      \
        for (int it = 0; it < 8; ++it) {                                       \
            int mid = (lo + hi + 1) >> 1;                                      \
            if (roff[mid] <= (j)) lo = mid; else hi = mid - 1;                 \
        }                                                                      \
        (srcv) = rsrc[lo] + ((j) - roff[lo]);                                  \
    }

    bool fits = (c <= (unsigned)BCAP);
    if (fits) {
        for (unsigned j = tid; j < c; j += TPB) {
            unsigned src; MAP_SRC(j, src);
            unsigned p = brp[src];
            unsigned cl = bcl[src];
            ebuf[j] = p; cbuf[j] = (u8)cl;
            atomicAdd(&cnt64[cl], 1u);
            atomicAdd(&dq[cl], p >> 17);
        }
        __syncthreads();
        if (tid == 0) {                                  // tiny serial scan of 64
            unsigned acc = 0;
            for (int i = 0; i < RB; i++) { st64[i] = acc; acc += cnt64[i]; cnt64[i] = 0u; }
        }
        __syncthreads();
        for (unsigned j = tid; j < c; j += TPB) {
            unsigned cl = cbuf[j];
            unsigned pos = st64[cl] + atomicAdd(&cnt64[cl], 1u);
            srt[s + pos] = ebuf[j];                      // within-bucket contiguous range
        }
    } else {                                             // 2-pass fallback (rare)
        for (unsigned j = tid; j < c; j += TPB) {
            unsigned src; MAP_SRC(j, src);
            unsigned cl = bcl[src];
            atomicAdd(&cnt64[cl], 1u);
            atomicAdd(&dq[cl], brp[src] >> 17);
        }
        __syncthreads();
        if (tid == 0) {
            unsigned acc = 0;
            for (int i = 0; i < RB; i++) { st64[i] = acc; acc += cnt64[i]; cnt64[i] = 0u; }
        }
        __syncthreads();
        for (unsigned j = tid; j < c; j += TPB) {
            unsigned src; MAP_SRC(j, src);
            unsigned cl = bcl[src];
            unsigned pos = st64[cl] + atomicAdd(&cnt64[cl], 1u);
            srt[s + pos] = brp[src];
        }
    }
    __syncthreads();
    if (tid < RB) {
        float d = rsqrtf(1.0f + (float)dq[tid] * (1.0f / 32768.0f));  // self-loop +1
        dl[tid] = d;
        if (tid < nn) {
            dinv[node0 + tid] = d;
            cptr[node0 + tid] = s + st64[tid];
        }
    }
    if (tid == 0 && node0 + nn == N) cptr[N] = (unsigned)E;  // sentinel
    __syncthreads();
    float* gtmp = (float*)ebuf;   // safe: all ebuf reads complete
    for (int idx2 = tid; idx2 < nn * 16; idx2 += TPB) {
        int n = idx2 >> 4, f = idx2 & 15;
        float vv = dl[n] * (lx[n * 3] * lw[f] + lx[n * 3 + 1] * lw[16 + f] +
                            lx[n * 3 + 2] * lw[32 + f]);
        acc1[(size_t)(node0 + n) * 16 + f] = vv;
        gtmp[idx2] = vv;
    }
    __syncthreads();
    for (int idx2 = tid; idx2 < nn * 8; idx2 += TPB) {
        int n = idx2 >> 3, qq = idx2 & 7;
        g1b[(size_t)(node0 + n) * 8 + qq] =
            (unsigned)f2bf(gtmp[n * 16 + 2 * qq]) |
            ((unsigned)f2bf(gtmp[n * 16 + 2 * qq + 1]) << 16);
    }
#undef MAP_SRC
}

// ---------- consumer: 8 lanes/col, serial register accumulate, no barriers ----------
__global__ __launch_bounds__(TPB)
void k_csr(const unsigned* __restrict__ srt, const unsigned* __restrict__ cptr,
           const unsigned* __restrict__ gb, float* __restrict__ acc, int N) {
    int t = blockIdx.x * TPB + threadIdx.x;
    int c = t >> 3, f2 = t & 7;
    if (c >= N) return;
    unsigned e = cptr[c], end = cptr[c + 1];
    float a = 0.0f, b = 0.0f;
#pragma unroll 4
    for (; e < end; ++e) {
        unsigned m = srt[e];                         // same addr across 8 lanes -> merged
        float w = (float)(m >> 17) * (1.0f / 32768.0f);
        unsigned u = gb[(size_t)(m & 0x1FFFFu) * 8 + f2];  // bf16x2, L2-resident table
        a = fmaf(w, __uint_as_float(u << 16), a);
        b = fmaf(w, __uint_as_float(u & 0xFFFF0000u), b);
    }
    float2* p = (float2*)&acc[(size_t)c * 16 + 2 * f2];
    float2 v = *p;                                   // exclusive owner: plain RMW
    v.x += a; v.y += b;
    *p = v;
}

// ---------- mid: h1 = relu(b1 + dinv*acc1); g2 = dinv*(h1@W2) -> bf16 + acc2 seed ----------
__global__ void k_mid(const float* __restrict__ acc1, const float* __restrict__ dinv,
                      const float* __restrict__ b1, const float* __restrict__ W2,
                      unsigned* __restrict__ g2b, float* __restrict__ acc2, int N) {
    __shared__ float t[16][16];
    __shared__ float go[16][16];
    __shared__ float w2[256];
    int tid = threadIdx.x;
    int il = tid >> 4, f = tid & 15;
    int i = blockIdx.x * 16 + il;
    w2[tid] = W2[tid];
    float v = 0.0f, d = 0.0f;
    if (i < N) {
        d = dinv[i];
        v = b1[f] + d * acc1[(size_t)i * 16 + f];
        v = v > 0.0f ? v : 0.0f;
    }
    t[il][f] = v;
    __syncthreads();
    float r = 0.0f;
    if (i < N) {
        float o = 0.0f;
#pragma unroll
        for (int kk = 0; kk < 16; kk++) o += t[il][kk] * w2[kk * 16 + f];
        r = d * o;
        acc2[(size_t)i * 16 + f] = r;
    }
    go[il][f] = r;
    __syncthreads();
    if (tid < 128) {
        int il2 = tid >> 3, q = tid & 7;
        int i2 = blockIdx.x * 16 + il2;
        if (i2 < N)
            g2b[(size_t)i2 * 8 + q] = (unsigned)f2bf(go[il2][2 * q]) |
                                      ((unsigned)f2bf(go[il2][2 * q + 1]) << 16);
    }
}

// ---------- pool: h2 = relu(b2 + dinv*acc2) folded into sorted-batch pool ----------
#define PC 1024
__global__ void k_pool(const float* __restrict__ acc2, const float* __restrict__ dinv,
                       const float* __restrict__ b2, const int* __restrict__ batch,
                       float* __restrict__ pooled, int N, int G) {
    int b0 = blockIdx.x * PC;
    int nodes = min(PC, N - b0);
    __shared__ float lacc[64 * 16];
    __shared__ int lbat[PC];
    int tid = threadIdx.x;  // 256
    for (int i = tid; i < nodes; i += 256) lbat[i] = batch[b0 + i];
    __syncthreads();
    int gmin = lbat[0], gmax = lbat[nodes - 1];
    bool fits = (gmax - gmin < 64);
    if (fits) {
        for (int i = tid; i < 64 * 16; i += 256) lacc[i] = 0.0f;
        __syncthreads();
    }
    for (int idx = tid; idx < nodes * 16; idx += 256) {
        int i = idx >> 4, f = idx & 15;
        int n = b0 + i;
        float d = dinv[n];
        float v = b2[f] + d * acc2[(size_t)n * 16 + f];
        v = v > 0.0f ? v : 0.0f;
        if (fits) atomicAdd(&lacc[(lbat[i] - gmin) * 16 + f], v);
        else      atomicAdd(&pooled[lbat[i] * 16 + f], v);
    }
    if (fits) {
        __syncthreads();
        for (int idx = tid; idx < 64 * 16; idx += 256) {
            int g = gmin + (idx >> 4);
            float v = lacc[idx];
            if (g < G && v != 0.0f) atomicAdd(&pooled[g * 16 + (idx & 15)], v);
        }
    }
}

__global__ void k_final(const float* __restrict__ pooled, const float* __restrict__ Wlin,
                        const float* __restrict__ blin, float* __restrict__ out, int G) {
    int t = blockIdx.x * blockDim.x + threadIdx.x;
    int g = t / 7, j = t % 7;
    if (g >= G) return;
    float v = blin[j];
#pragma unroll
    for (int f = 0; f < 16; f++) v += pooled[g * 16 + f] * Wlin[f * 7 + j];
    out[g * 7 + j] = v;
}

static inline int cdiv_i(long long a, long long b) { return (int)((a + b - 1) / b); }

extern "C" void kernel_launch(void* const* d_in, const int* in_sizes, int n_in,
                              void* d_out, int out_size, void* d_ws, size_t ws_size,
                              hipStream_t stream) {
    const float* x     = (const float*)d_in[0];
    const int*   ei    = (const int*)d_in[1];
    const float* ew    = (const float*)d_in[2];
    const int*   batch = (const int*)d_in[3];
    const float* W1    = (const float*)d_in[4];
    const float* b1    = (const float*)d_in[5];
    const float* W2    = (const float*)d_in[6];
    const float* b2    = (const float*)d_in[7];
    const float* Wlin  = (const float*)d_in[8];
    const float* blin  = (const float*)d_in[9];
    float* out = (float*)d_out;

    const int N = in_sizes[0] / 3;
    const int E = in_sizes[2];
    const int G = out_size / 7;
    const int K = (N + RB - 1) >> SH;   // 1563
    const int tile = cdiv_i(E, PB);
    const int* row = ei;
    const int* col = ei + E;

    // layout: [zero: bcnt, pooled] | bst | bh | bof | brp | bcl | srt | cptr | dinv | g1b | g2b | acc1 | acc2
    unsigned* bcnt   = (unsigned*)d_ws;                     // KMAX
    float*    pooled = (float*)(bcnt + KMAX);               // G*16
    unsigned* bst    = (unsigned*)(pooled + (size_t)G*16);  // KMAX
    unsigned* bh     = bst + KMAX;                          // PB*KMAX
    unsigned* bof    = bh + (size_t)PB * KMAX;              // PB*KST
    unsigned* brp    = bof + (size_t)PB * KST;              // E
    u8*       bcl    = (u8*)(brp + E);                      // E (E%4==0)
    unsigned* srt    = (unsigned*)(bcl + E);                // E
    unsigned* cptr   = srt + E;                             // N+1
    float*    dinv   = (float*)(cptr + N + 1);              // N
    unsigned* g1b    = (unsigned*)(dinv + N);               // N*8 (bf16 x16)
    unsigned* g2b    = g1b + (size_t)N * 8;                 // N*8
    float*    acc1   = (float*)(g2b + (size_t)N * 8);       // N*16
    float*    acc2   = acc1 + (size_t)N * 16;               // N*16

    hipMemsetAsync(d_ws, 0, (KMAX + (size_t)G * 16) * sizeof(unsigned), stream);

    // CSR build: tiled counts(+bh) -> bst scan -> block-major partition -> run-gather group
    k_cnt<<<PB, TPB, 0, stream>>>(col, bcnt, bh, E, K, tile);
    k_scan<<<1, 1024, 0, stream>>>(bcnt, bst, K);
    k_part<<<PB, PT, 0, stream>>>(row, col, ew, bh, bof, brp, bcl, E, K, tile);
    k_grp<<<K, TPB, 0, stream>>>(brp, bcl, bof, bst, x, W1, srt, cptr, dinv, g1b, acc1,
                                 N, E, K);

    // layer 1: barrier-free CSR gather/reduce
    k_csr<<<cdiv_i((long long)N * 8, TPB), TPB, 0, stream>>>(srt, cptr, g1b, acc1, N);

    // mid: h1 -> g2(bf16) + acc2 seed
    k_mid<<<cdiv_i(N, 16), TPB, 0, stream>>>(acc1, dinv, b1, W2, g2b, acc2, N);

    // layer 2
    k_csr<<<cdiv_i((long long)N * 8, TPB), TPB, 0, stream>>>(srt, cptr, g2b, acc2, N);

    // pool + head
    k_pool<<<cdiv_i(N, PC), TPB, 0, stream>>>(acc2, dinv, b2, batch, pooled, N, G);
    k_final<<<cdiv_i((long long)G * 7, TPB), TPB, 0, stream>>>(pooled, Wlin, blin, out, G);
}

// Round 6
// 280.459 us; speedup vs baseline: 1.1429x; 1.1429x over previous
//
#include <hip/hip_runtime.h>

// GCN 2-layer + pool + head, R21: occupancy + payload + run-map fixes on R20.
// R20: k_part 69us at 9.5% occ (grid 256 x 256thr = 4 waves/CU) with WRITE 85MB/16MB
// payload (byte-wide bcl stores thrash 64B lines: 64 scattered 1B writes per line over
// the block's lifetime); k_grp's 8-step per-edge binary search added ~35us vs R19.
// Fixes: (a) k_part/k_cnt 1024 threads (16 waves/CU, 4x latency hiding for the scatter);
// (b) payload = ONE aligned uint2 store (row|wq15<<17, col) - no byte stores;
// (c) k_grp maps edge->source via u8 seg[] stamp (2 LDS reads) instead of binary search.
// Pipeline: k_cnt(bh) -> k_scan -> k_part(block-major private regions, L2-resident)
//        -> k_grp(run-gather, group-by-col -> srt/cptr/dinv/g1b/acc1) -> k_csr x2
//        -> k_mid -> k_pool -> k_final.
//   h[c] = b + dinv[c]*( g[c] + sum_e w_e * g[row_e] ),  g = dinv * (prev @ W)

#define SH 6
#define RB 64
#define KMAX 2048           // N <= 131072 (row packs in 17 bits)
#define TPB 256
#define BCAP 8192           // per-bucket LDS capacity in k_grp
#define CT 1024             // k_cnt threads
#define PT 1024             // k_part threads
#define PB 256              // partition grid (= k_cnt grid)
#define KST (KMAX + 1)      // bof row stride

typedef unsigned short ushort_t;
typedef unsigned char u8;

__device__ __forceinline__ ushort_t f2bf(float v) {
    unsigned u = __float_as_uint(v);
    u += 0x7FFFu + ((u >> 16) & 1u);   // RNE
    return (ushort_t)(u >> 16);
}

__device__ __forceinline__ unsigned quantw(float w) {
    unsigned wq = (unsigned)__float2int_rn(w * 32768.0f);
    return wq > 32767u ? 32767u : wq;
}

// ---------- bucket counts, tile-aligned; stores per-block hist for k_part ----------
__global__ __launch_bounds__(CT)
void k_cnt(const int* __restrict__ col, unsigned* __restrict__ bcnt,
           unsigned* __restrict__ bh, int E, int K, int tile) {
    __shared__ unsigned lh[KMAX];
    int e0 = blockIdx.x * tile, e1 = min(e0 + tile, E);
    for (int i = threadIdx.x; i < K; i += CT) lh[i] = 0u;
    __syncthreads();
    for (int e = e0 + threadIdx.x; e < e1; e += CT)
        atomicAdd(&lh[col[e] >> SH], 1u);
    __syncthreads();
    for (int i = threadIdx.x; i < K; i += CT) {
        unsigned c = lh[i];
        bh[(size_t)blockIdx.x * KMAX + i] = c;
        if (c) atomicAdd(&bcnt[i], c);
    }
}

// ---------- exclusive scan over bucket counts -> bst (srt layout) ----------
__global__ void k_scan(const unsigned* __restrict__ cnt, unsigned* __restrict__ start,
                       int K) {
    __shared__ unsigned a[KMAX], b[KMAX];
    int t = threadIdx.x;  // 1024
    for (int i = t; i < KMAX; i += 1024) a[i] = (i < K) ? cnt[i] : 0u;
    __syncthreads();
    unsigned *src = a, *dst = b;
    for (int off = 1; off < KMAX; off <<= 1) {
        for (int i = t; i < KMAX; i += 1024)
            dst[i] = (i >= off) ? src[i] + src[i - off] : src[i];
        __syncthreads();
        unsigned* tmp = src; src = dst; dst = tmp;
    }
    for (int i = t; i < K; i += 1024) start[i] = (i == 0) ? 0u : src[i - 1];
}

// ---------- block-major partition: private region, bucket-grouped, L2-resident ----------
__global__ __launch_bounds__(PT)
void k_part(const int* __restrict__ row, const int* __restrict__ col,
            const float* __restrict__ ew, const unsigned* __restrict__ bh,
            unsigned* __restrict__ bof, uint2* __restrict__ brc,
            int E, int K, int tile) {
    __shared__ unsigned lcur[KMAX];              // 8KB scatter cursors
    __shared__ unsigned wt[PT / 64];
    int tid = threadIdx.x, b = blockIdx.x;
    int e0 = b * tile; if (e0 > E) e0 = E;
    int e1 = min(b * tile + tile, E);
    unsigned base = (unsigned)e0;

    // exclusive scan of this block's bh row (KMAX entries, 2 serial per thread)
    int i0 = tid << 1;
    unsigned a0 = (i0 < K) ? bh[(size_t)b * KMAX + i0] : 0u;
    unsigned a1 = (i0 + 1 < K) ? bh[(size_t)b * KMAX + i0 + 1] : 0u;
    unsigned ts = a0 + a1;
    unsigned v = ts;
#pragma unroll
    for (int o = 1; o < 64; o <<= 1) {
        unsigned u = __shfl_up(v, o, 64);
        if ((tid & 63) >= o) v += u;
    }
    if ((tid & 63) == 63) wt[tid >> 6] = v;
    __syncthreads();
    if (tid == 0) {
        unsigned acc = 0;
#pragma unroll
        for (int w = 0; w < PT / 64; w++) { unsigned t = wt[w]; wt[w] = acc; acc += t; }
    }
    __syncthreads();
    unsigned ex = wt[tid >> 6] + (v - ts);       // exclusive prefix at i0
    unsigned* bo = bof + (size_t)b * KST;        // streaming row write
    lcur[i0] = base + ex;       bo[i0] = base + ex;
    lcur[i0 + 1] = base + ex + a0;  bo[i0 + 1] = base + ex + a0;
    if (tid == PT - 1) bo[KMAX] = base + ex + ts;
    __syncthreads();

    // streaming scatter into private region (random within ~100KB -> L2 absorbs)
    for (int e = e0 + tid; e < e1; e += PT) {
        int c = col[e];
        unsigned pos = atomicAdd(&lcur[c >> SH], 1u);
        brc[pos] = make_uint2((unsigned)row[e] | (quantw(ew[e]) << 17), (unsigned)c);
    }
}

// ---------- per-bucket: gather 256 runs -> group-by-col -> srt + cptr + dinv + g1/acc1 ----
__global__ __launch_bounds__(TPB)
void k_grp(const uint2* __restrict__ brc, const unsigned* __restrict__ bof,
           const unsigned* __restrict__ bst, const float* __restrict__ x,
           const float* __restrict__ W1, unsigned* __restrict__ srt,
           unsigned* __restrict__ cptr, float* __restrict__ dinv,
           unsigned* __restrict__ g1b, float* __restrict__ acc1,
           int N, int E, int K) {
    // bijective XCD-contiguous swizzle (m204): consecutive buckets share an XCD's L2
    int orig = blockIdx.x;
    int q8 = K >> 3, r8 = K & 7;
    int xcd = orig & 7, idx = orig >> 3;
    int k = (xcd < r8 ? xcd * (q8 + 1) : r8 * (q8 + 1) + (xcd - r8) * q8) + idx;
    int node0 = k << SH;

    __shared__ unsigned ebuf[BCAP];          // 32KB (reused as gtmp after scatter)
    __shared__ u8 cbuf[BCAP];                // 8KB
    __shared__ u8 seg[BCAP];                 // 8KB: j -> run id
    __shared__ unsigned rsrc[PB];            // run source starts
    __shared__ unsigned roff[PB + 1];        // exclusive prefix of run lengths
    __shared__ unsigned wt4[TPB / 64];
    __shared__ unsigned cnt64[RB], st64[RB], dq[RB];
    __shared__ float dl[RB], lx[RB * 3], lw[48];
    int tid = threadIdx.x;
    unsigned s = bst[k];
    if (tid < RB) { cnt64[tid] = 0u; dq[tid] = 0u; }
    if (tid < 48) lw[tid] = W1[tid];
    int nn = min(RB, N - node0);
    for (int i = tid; i < nn * 3; i += TPB) lx[i] = x[(size_t)node0 * 3 + i];

    // run table: rsrc/len from bof columns k, k+1; 256-entry exclusive scan
    unsigned rl;
    {
        unsigned s0 = bof[(size_t)tid * KST + k];
        unsigned s1 = bof[(size_t)tid * KST + k + 1];
        rsrc[tid] = s0;
        rl = s1 - s0;
    }
    unsigned v = rl;
#pragma unroll
    for (int o = 1; o < 64; o <<= 1) {
        unsigned u = __shfl_up(v, o, 64);
        if ((tid & 63) >= o) v += u;
    }
    if ((tid & 63) == 63) wt4[tid >> 6] = v;
    __syncthreads();
    if (tid == 0) {
        unsigned acc = 0;
#pragma unroll
        for (int w = 0; w < TPB / 64; w++) { unsigned t = wt4[w]; wt4[w] = acc; acc += t; }
    }
    __syncthreads();
    unsigned ex = wt4[tid >> 6] + (v - rl);
    roff[tid] = ex;
    if (tid == PB - 1) roff[PB] = ex + rl;
    __syncthreads();
    unsigned c = roff[PB];

    bool fits = (c <= (unsigned)BCAP);
    if (fits) {
        for (unsigned j = ex; j < ex + rl; ++j) seg[j] = (u8)tid;  // stamp run ids
        __syncthreads();
        for (unsigned j = tid; j < c; j += TPB) {
            unsigned r = seg[j];
            unsigned src = rsrc[r] + (j - roff[r]);
            uint2 p = brc[src];
            unsigned cl = p.y & 63u;
            ebuf[j] = p.x; cbuf[j] = (u8)cl;
            atomicAdd(&cnt64[cl], 1u);
            atomicAdd(&dq[cl], p.x >> 17);
        }
        __syncthreads();
        if (tid == 0) {                                  // tiny serial scan of 64
            unsigned acc = 0;
            for (int i = 0; i < RB; i++) { st64[i] = acc; acc += cnt64[i]; cnt64[i] = 0u; }
        }
        __syncthreads();
        for (unsigned j = tid; j < c; j += TPB) {
            unsigned cl = cbuf[j];
            unsigned pos = st64[cl] + atomicAdd(&cnt64[cl], 1u);
            srt[s + pos] = ebuf[j];                      // within-bucket contiguous range
        }
    } else {                                             // 2-pass fallback (rare): bsearch
#define MAP_SRC(j, srcv)                                                       \
        {                                                                      \
            int lo = 0, hi = PB - 1;                                           \
            _Pragma("unroll")                                                  \
            for (int it = 0; it < 8; ++it) {                                   \
                int mid = (lo + hi + 1) >> 1;                                  \
                if (roff[mid] <= (j)) lo = mid; else hi = mid - 1;             \
            }                                                                  \
            (srcv) = rsrc[lo] + ((j) - roff[lo]);                              \
        }
        for (unsigned j = tid; j < c; j += TPB) {
            unsigned src; MAP_SRC(j, src);
            uint2 p = brc[src];
            unsigned cl = p.y & 63u;
            atomicAdd(&cnt64[cl], 1u);
            atomicAdd(&dq[cl], p.x >> 17);
        }
        __syncthreads();
        if (tid == 0) {
            unsigned acc = 0;
            for (int i = 0; i < RB; i++) { st64[i] = acc; acc += cnt64[i]; cnt64[i] = 0u; }
        }
        __syncthreads();
        for (unsigned j = tid; j < c; j += TPB) {
            unsigned src; MAP_SRC(j, src);
            uint2 p = brc[src];
            unsigned cl = p.y & 63u;
            unsigned pos = st64[cl] + atomicAdd(&cnt64[cl], 1u);
            srt[s + pos] = p.x;
        }
#undef MAP_SRC
    }
    __syncthreads();
    if (tid < RB) {
        float d = rsqrtf(1.0f + (float)dq[tid] * (1.0f / 32768.0f));  // self-loop +1
        dl[tid] = d;
        if (tid < nn) {
            dinv[node0 + tid] = d;
            cptr[node0 + tid] = s + st64[tid];
        }
    }
    if (tid == 0 && node0 + nn == N) cptr[N] = (unsigned)E;  // sentinel
    __syncthreads();
    float* gtmp = (float*)ebuf;   // safe: all ebuf reads complete
    for (int idx2 = tid; idx2 < nn * 16; idx2 += TPB) {
        int n = idx2 >> 4, f = idx2 & 15;
        float vv = dl[n] * (lx[n * 3] * lw[f] + lx[n * 3 + 1] * lw[16 + f] +
                            lx[n * 3 + 2] * lw[32 + f]);
        acc1[(size_t)(node0 + n) * 16 + f] = vv;
        gtmp[idx2] = vv;
    }
    __syncthreads();
    for (int idx2 = tid; idx2 < nn * 8; idx2 += TPB) {
        int n = idx2 >> 3, qq = idx2 & 7;
        g1b[(size_t)(node0 + n) * 8 + qq] =
            (unsigned)f2bf(gtmp[n * 16 + 2 * qq]) |
            ((unsigned)f2bf(gtmp[n * 16 + 2 * qq + 1]) << 16);
    }
}

// ---------- consumer: 8 lanes/col, serial register accumulate, no barriers ----------
__global__ __launch_bounds__(TPB)
void k_csr(const unsigned* __restrict__ srt, const unsigned* __restrict__ cptr,
           const unsigned* __restrict__ gb, float* __restrict__ acc, int N) {
    int t = blockIdx.x * TPB + threadIdx.x;
    int c = t >> 3, f2 = t & 7;
    if (c >= N) return;
    unsigned e = cptr[c], end = cptr[c + 1];
    float a = 0.0f, b = 0.0f;
#pragma unroll 4
    for (; e < end; ++e) {
        unsigned m = srt[e];                         // same addr across 8 lanes -> merged
        float w = (float)(m >> 17) * (1.0f / 32768.0f);
        unsigned u = gb[(size_t)(m & 0x1FFFFu) * 8 + f2];  // bf16x2, L2-resident table
        a = fmaf(w, __uint_as_float(u << 16), a);
        b = fmaf(w, __uint_as_float(u & 0xFFFF0000u), b);
    }
    float2* p = (float2*)&acc[(size_t)c * 16 + 2 * f2];
    float2 v = *p;                                   // exclusive owner: plain RMW
    v.x += a; v.y += b;
    *p = v;
}

// ---------- mid: h1 = relu(b1 + dinv*acc1); g2 = dinv*(h1@W2) -> bf16 + acc2 seed ----------
__global__ void k_mid(const float* __restrict__ acc1, const float* __restrict__ dinv,
                      const float* __restrict__ b1, const float* __restrict__ W2,
                      unsigned* __restrict__ g2b, float* __restrict__ acc2, int N) {
    __shared__ float t[16][16];
    __shared__ float go[16][16];
    __shared__ float w2[256];
    int tid = threadIdx.x;
    int il = tid >> 4, f = tid & 15;
    int i = blockIdx.x * 16 + il;
    w2[tid] = W2[tid];
    float v = 0.0f, d = 0.0f;
    if (i < N) {
        d = dinv[i];
        v = b1[f] + d * acc1[(size_t)i * 16 + f];
        v = v > 0.0f ? v : 0.0f;
    }
    t[il][f] = v;
    __syncthreads();
    float r = 0.0f;
    if (i < N) {
        float o = 0.0f;
#pragma unroll
        for (int kk = 0; kk < 16; kk++) o += t[il][kk] * w2[kk * 16 + f];
        r = d * o;
        acc2[(size_t)i * 16 + f] = r;
    }
    go[il][f] = r;
    __syncthreads();
    if (tid < 128) {
        int il2 = tid >> 3, q = tid & 7;
        int i2 = blockIdx.x * 16 + il2;
        if (i2 < N)
            g2b[(size_t)i2 * 8 + q] = (unsigned)f2bf(go[il2][2 * q]) |
                                      ((unsigned)f2bf(go[il2][2 * q + 1]) << 16);
    }
}

// ---------- pool: h2 = relu(b2 + dinv*acc2) folded into sorted-batch pool ----------
#define PC 1024
__global__ void k_pool(const float* __restrict__ acc2, const float* __restrict__ dinv,
                       const float* __restrict__ b2, const int* __restrict__ batch,
                       float* __restrict__ pooled, int N, int G) {
    int b0 = blockIdx.x * PC;
    int nodes = min(PC, N - b0);
    __shared__ float lacc[64 * 16];
    __shared__ int lbat[PC];
    int tid = threadIdx.x;  // 256
    for (int i = tid; i < nodes; i += 256) lbat[i] = batch[b0 + i];
    __syncthreads();
    int gmin = lbat[0], gmax = lbat[nodes - 1];
    bool fits = (gmax - gmin < 64);
    if (fits) {
        for (int i = tid; i < 64 * 16; i += 256) lacc[i] = 0.0f;
        __syncthreads();
    }
    for (int idx = tid; idx < nodes * 16; idx += 256) {
        int i = idx >> 4, f = idx & 15;
        int n = b0 + i;
        float d = dinv[n];
        float v = b2[f] + d * acc2[(size_t)n * 16 + f];
        v = v > 0.0f ? v : 0.0f;
        if (fits) atomicAdd(&lacc[(lbat[i] - gmin) * 16 + f], v);
        else      atomicAdd(&pooled[lbat[i] * 16 + f], v);
    }
    if (fits) {
        __syncthreads();
        for (int idx = tid; idx < 64 * 16; idx += 256) {
            int g = gmin + (idx >> 4);
            float v = lacc[idx];
            if (g < G && v != 0.0f) atomicAdd(&pooled[g * 16 + (idx & 15)], v);
        }
    }
}

__global__ void k_final(const float* __restrict__ pooled, const float* __restrict__ Wlin,
                        const float* __restrict__ blin, float* __restrict__ out, int G) {
    int t = blockIdx.x * blockDim.x + threadIdx.x;
    int g = t / 7, j = t % 7;
    if (g >= G) return;
    float v = blin[j];
#pragma unroll
    for (int f = 0; f < 16; f++) v += pooled[g * 16 + f] * Wlin[f * 7 + j];
    out[g * 7 + j] = v;
}

static inline int cdiv_i(long long a, long long b) { return (int)((a + b - 1) / b); }

extern "C" void kernel_launch(void* const* d_in, const int* in_sizes, int n_in,
                              void* d_out, int out_size, void* d_ws, size_t ws_size,
                              hipStream_t stream) {
    const float* x     = (const float*)d_in[0];
    const int*   ei    = (const int*)d_in[1];
    const float* ew    = (const float*)d_in[2];
    const int*   batch = (const int*)d_in[3];
    const float* W1    = (const float*)d_in[4];
    const float* b1    = (const float*)d_in[5];
    const float* W2    = (const float*)d_in[6];
    const float* b2    = (const float*)d_in[7];
    const float* Wlin  = (const float*)d_in[8];
    const float* blin  = (const float*)d_in[9];
    float* out = (float*)d_out;

    const int N = in_sizes[0] / 3;
    const int E = in_sizes[2];
    const int G = out_size / 7;
    const int K = (N + RB - 1) >> SH;   // 1563
    const int tile = cdiv_i(E, PB);
    const int* row = ei;
    const int* col = ei + E;

    // layout: [zero: bcnt, pooled] | bst | bh | bof | brc(uint2) | srt | cptr | dinv | g1b | g2b | acc1 | acc2
    unsigned* bcnt   = (unsigned*)d_ws;                     // KMAX
    float*    pooled = (float*)(bcnt + KMAX);               // G*16
    unsigned* bst    = (unsigned*)(pooled + (size_t)G*16);  // KMAX
    unsigned* bh     = bst + KMAX;                          // PB*KMAX
    unsigned* bof    = bh + (size_t)PB * KMAX;              // PB*KST
    uint2*    brc    = (uint2*)(bof + (size_t)PB * KST);    // E (8B each)
    unsigned* srt    = (unsigned*)(brc + E);                // E
    unsigned* cptr   = srt + E;                             // N+1
    float*    dinv   = (float*)(cptr + N + 1);              // N
    unsigned* g1b    = (unsigned*)(dinv + N);               // N*8 (bf16 x16)
    unsigned* g2b    = g1b + (size_t)N * 8;                 // N*8
    float*    acc1   = (float*)(g2b + (size_t)N * 8);       // N*16
    float*    acc2   = acc1 + (size_t)N * 16;               // N*16

    hipMemsetAsync(d_ws, 0, (KMAX + (size_t)G * 16) * sizeof(unsigned), stream);

    // CSR build: tiled counts(+bh) -> bst scan -> block-major partition -> run-gather group
    k_cnt<<<PB, CT, 0, stream>>>(col, bcnt, bh, E, K, tile);
    k_scan<<<1, 1024, 0, stream>>>(bcnt, bst, K);
    k_part<<<PB, PT, 0, stream>>>(row, col, ew, bh, bof, brc, E, K, tile);
    k_grp<<<K, TPB, 0, stream>>>(brc, bof, bst, x, W1, srt, cptr, dinv, g1b, acc1,
                                 N, E, K);

    // layer 1: barrier-free CSR gather/reduce
    k_csr<<<cdiv_i((long long)N * 8, TPB), TPB, 0, stream>>>(srt, cptr, g1b, acc1, N);

    // mid: h1 -> g2(bf16) + acc2 seed
    k_mid<<<cdiv_i(N, 16), TPB, 0, stream>>>(acc1, dinv, b1, W2, g2b, acc2, N);

    // layer 2
    k_csr<<<cdiv_i((long long)N * 8, TPB), TPB, 0, stream>>>(srt, cptr, g2b, acc2, N);

    // pool + head
    k_pool<<<cdiv_i(N, PC), TPB, 0, stream>>>(acc2, dinv, b2, batch, pooled, N, G);
    k_final<<<cdiv_i((long long)G * 7, TPB), TPB, 0, stream>>>(pooled, Wlin, blin, out, G);
}